// Round 4
// baseline (423.888 us; speedup 1.0000x reference)
//
#include <hip/hip_runtime.h>
#include <cstdint>
#include <cstddef>

#define NB 2
#define NL 2048
#define ND 1024
#define NH 16
#define NDH 64
#define NDFF 4096

typedef __bf16 bf16_t;
typedef bf16_t bf16x8 __attribute__((ext_vector_type(8)));
typedef float f32x4 __attribute__((ext_vector_type(4)));

__device__ __forceinline__ float bf2f(unsigned short h) {
  union { unsigned u; float f; } c; c.u = ((unsigned)h) << 16; return c.f;
}
__device__ __forceinline__ unsigned short f2bf(float f) {
  union { float f; unsigned u; } c; c.f = f;
  return (unsigned short)((c.u + 0x7fffu + ((c.u >> 16) & 1u)) >> 16);
}

// async global->LDS, 16B per lane; lds base must be wave-uniform.
__device__ __forceinline__ void async_copy16(const void* g, void* l) {
  __builtin_amdgcn_global_load_lds(
      (const __attribute__((address_space(1))) void*)g,
      (__attribute__((address_space(3))) void*)l, 16, 0, 0);
}

// ---------------------------------------------------------------------------
// f32 -> bf16 cast, vec4.
// ---------------------------------------------------------------------------
__global__ __launch_bounds__(256) void cast_f32_bf16(
    const float* __restrict__ in, unsigned short* __restrict__ out, int n4) {
  const int i = blockIdx.x * 256 + threadIdx.x;
  if (i >= n4) return;
  const float4 v = ((const float4*)in)[i];
  ushort4 o;
  o.x = f2bf(v.x); o.y = f2bf(v.y); o.z = f2bf(v.z); o.w = f2bf(v.w);
  ((ushort4*)out)[i] = o;
}

// ---------------------------------------------------------------------------
// GEMM: C[M,N] = A[M,K] @ W[N,K]^T + bias[N]  (A,W bf16; bias f32; C bf16/f32)
// 128x128 tile, BK=32, 4 waves 2x2, 4x4 mfma_f32_16x16x32_bf16 per wave.
// m97 structure: global_load_lds width-16 staging, 2 barriers per K-iter.
// ---------------------------------------------------------------------------
template <bool RELU, bool OUT_BF16>
__global__ __launch_bounds__(256, 2) void gemm_bt(
    const unsigned short* __restrict__ A, const unsigned short* __restrict__ W,
    const float* __restrict__ bias, unsigned short* __restrict__ outb,
    float* __restrict__ outf, int M, int N, int K) {
  const int tid = threadIdx.x;
  const int wave = tid >> 6, lane = tid & 63;
  const int quad = lane >> 4, l16 = lane & 15;
  const int wm = wave & 1, wn = wave >> 1;
  const int m0 = blockIdx.y * 128, n0 = blockIdx.x * 128;

  __shared__ __align__(16) unsigned short As[128 * 32];
  __shared__ __align__(16) unsigned short Bs[128 * 32];

  const int r0 = tid >> 2;       // 0..63
  const int kc = (tid & 3) * 8;  // 0,8,16,24
  const unsigned short* Ag0 = A + (size_t)(m0 + r0) * K + kc;
  const unsigned short* Ag1 = A + (size_t)(m0 + r0 + 64) * K + kc;
  const unsigned short* Bg0 = W + (size_t)(n0 + r0) * K + kc;
  const unsigned short* Bg1 = W + (size_t)(n0 + r0 + 64) * K + kc;
  // wave-uniform LDS bases; lane's 16B lands at base + lane*16
  unsigned short* AsW0 = &As[(wave * 64) * 8];
  unsigned short* AsW1 = &As[(256 + wave * 64) * 8];
  unsigned short* BsW0 = &Bs[(wave * 64) * 8];
  unsigned short* BsW1 = &Bs[(256 + wave * 64) * 8];

  f32x4 acc[4][4];
#pragma unroll
  for (int i = 0; i < 4; i++)
#pragma unroll
    for (int j = 0; j < 4; j++) acc[i][j] = (f32x4){0.f, 0.f, 0.f, 0.f};

  for (int k0 = 0; k0 < K; k0 += 32) {
    __syncthreads();  // prior iteration's ds_reads complete
    async_copy16(Ag0 + k0, AsW0);
    async_copy16(Ag1 + k0, AsW1);
    async_copy16(Bg0 + k0, BsW0);
    async_copy16(Bg1 + k0, BsW1);
    __syncthreads();  // drains vmcnt(0): staging landed
    bf16x8 af[4], bfr[4];
#pragma unroll
    for (int i = 0; i < 4; i++)
      af[i] = *(const bf16x8*)&As[(wm * 64 + i * 16 + l16) * 32 + quad * 8];
#pragma unroll
    for (int j = 0; j < 4; j++)
      bfr[j] = *(const bf16x8*)&Bs[(wn * 64 + j * 16 + l16) * 32 + quad * 8];
#pragma unroll
    for (int i = 0; i < 4; i++)
#pragma unroll
      for (int j = 0; j < 4; j++)
        acc[i][j] =
            __builtin_amdgcn_mfma_f32_16x16x32_bf16(af[i], bfr[j], acc[i][j], 0, 0, 0);
  }

#pragma unroll
  for (int j = 0; j < 4; j++) {
    const int col = n0 + wn * 64 + j * 16 + l16;
    const float bj = bias[col];
#pragma unroll
    for (int i = 0; i < 4; i++) {
      const int rowb = m0 + wm * 64 + i * 16 + quad * 4;
#pragma unroll
      for (int r = 0; r < 4; r++) {
        float v = acc[i][j][r] + bj;
        if (RELU) v = v > 0.f ? v : 0.f;
        const size_t idx = (size_t)(rowb + r) * N + col;
        if (OUT_BF16) outb[idx] = f2bf(v);
        else outf[idx] = v;
      }
    }
  }
}

// ---------------------------------------------------------------------------
// MFMA flash attention, causal. qkv: [B*L][3*ND] bf16, row = [q | k | v].
// Block = 4 waves, 128 q rows. Wave w owns INTERLEAVED groups
// {q0+w*16, q0+64+w*16} so causal cutoffs are balanced across waves.
// K/V register-prefetched one chunk ahead (global latency overlaps compute).
// qt remapped so co-resident block pairs (i, i+256) have equal total work.
// ---------------------------------------------------------------------------
__global__ __launch_bounds__(256, 2) void attn_mfma(
    const unsigned short* __restrict__ qkv, unsigned short* __restrict__ out) {
  const int tid = threadIdx.x;
  const int w = tid >> 6, lane = tid & 63;
  const int quad = lane >> 4, l16 = lane & 15;
  const int bh = blockIdx.x;
  const int b = bh >> 4, h = bh & 15;
  const int y = blockIdx.y;
  const int qt = (y < 8) ? (15 - 2 * y) : (2 * (y - 8));  // pairs sum const
  const int q0 = qt * 128;
  const int qA = q0 + w * 16;       // group 0 rows
  const int qB = q0 + 64 + w * 16;  // group 1 rows

  __shared__ __align__(16) unsigned short Ks[64 * 72];     // [k][d]
  __shared__ __align__(16) unsigned short Vt[64 * 72];     // [d][k-swizzled]
  __shared__ __align__(16) unsigned short Pw[4][32 * 72];  // per-wave P [q][k]

  // Q B-frags (x0.125 folded, exact): qb[q2][kd]
  bf16x8 qb[2][2];
#pragma unroll
  for (int q2 = 0; q2 < 2; q2++)
#pragma unroll
    for (int kd = 0; kd < 2; kd++) {
      const int qrow = (q2 == 0 ? qA : qB) + l16;
      const unsigned short* qp =
          qkv + (size_t)(b * NL + qrow) * (3 * ND) + h * NDH + kd * 32 + quad * 8;
      union { uint4 u; unsigned short s[8]; bf16x8 v; } qu;
      qu.u = *(const uint4*)qp;
#pragma unroll
      for (int e = 0; e < 8; e++) qu.s[e] = f2bf(bf2f(qu.s[e]) * 0.125f);
      qb[q2][kd] = qu.v;
    }

  float m_s[2] = {-INFINITY, -INFINITY};
  float l_s[2] = {0.f, 0.f};
  f32x4 of_[2][4];
#pragma unroll
  for (int mt = 0; mt < 2; mt++)
#pragma unroll
    for (int nd = 0; nd < 4; nd++) of_[mt][nd] = (f32x4){0.f, 0.f, 0.f, 0.f};

  const int nch = 2 * (qt + 1);
  const int kk0 = tid >> 3;        // 0..31
  const int d0 = (tid & 7) * 8;
  const unsigned short* kvrow = qkv + (size_t)b * NL * 3 * ND + ND + h * NDH + d0;

  uint4 ku[2], vu[2];
#pragma unroll
  for (int p = 0; p < 2; p++) {
    const unsigned short* g = kvrow + (size_t)(p * 32 + kk0) * (3 * ND);
    ku[p] = *(const uint4*)g;
    vu[p] = *(const uint4*)(g + ND);
  }

  for (int c = 0; c < nch; c++) {
    const int kbase = c * 64;
    __syncthreads();  // prior chunk's Ks/Vt reads complete
    // ---- stage K (row-major) and V (transposed, swizzled k-groups) ----
#pragma unroll
    for (int p = 0; p < 2; p++) {
      const int kk = p * 32 + kk0;
      *(uint4*)&Ks[kk * 72 + d0] = ku[p];
      const unsigned short* pv = (const unsigned short*)&vu[p];
      const int kg = kk >> 3, kr = kk & 7;
#pragma unroll
      for (int e = 0; e < 8; e++) {
        const int d = d0 + e;
        Vt[d * 72 + ((kg ^ (d >> 3)) & 7) * 8 + kr] = pv[e];
      }
    }
    __syncthreads();
    // ---- prefetch next chunk (latency overlaps compute below) ----
    if (c + 1 < nch) {
#pragma unroll
      for (int p = 0; p < 2; p++) {
        const unsigned short* g =
            kvrow + (size_t)(kbase + 64 + p * 32 + kk0) * (3 * ND);
        ku[p] = *(const uint4*)g;
        vu[p] = *(const uint4*)(g + ND);
      }
    }

    if (kbase > qB + 15) continue;           // wave fully masked this chunk
    const bool actA = (kbase <= qA + 15);    // group A still active?

    // ---- S^T = K·Q^T: st[kt][q2], row=k(quad*4+reg), col=q(l16) ----
    f32x4 st[4][2];
#pragma unroll
    for (int kt = 0; kt < 4; kt++)
#pragma unroll
      for (int q2 = 0; q2 < 2; q2++) st[kt][q2] = (f32x4){0.f, 0.f, 0.f, 0.f};
#pragma unroll
    for (int kd = 0; kd < 2; kd++)
#pragma unroll
      for (int kt = 0; kt < 4; kt++) {
        const bf16x8 kaf =
            *(const bf16x8*)&Ks[(kt * 16 + l16) * 72 + kd * 32 + quad * 8];
        if (actA)
          st[kt][0] = __builtin_amdgcn_mfma_f32_16x16x32_bf16(kaf, qb[0][kd],
                                                              st[kt][0], 0, 0, 0);
        st[kt][1] = __builtin_amdgcn_mfma_f32_16x16x32_bf16(kaf, qb[1][kd],
                                                            st[kt][1], 0, 0, 0);
      }

    // ---- causal mask (boundary chunks only, per group) ----
    if (actA && kbase + 63 > qA) {
#pragma unroll
      for (int kt = 0; kt < 4; kt++) {
        const int kg_ = kbase + kt * 16 + quad * 4;
        const int qg_ = qA + l16;
#pragma unroll
        for (int r = 0; r < 4; r++)
          if (kg_ + r > qg_) st[kt][0][r] = -INFINITY;
      }
    }
    if (kbase + 63 > qB) {
#pragma unroll
      for (int kt = 0; kt < 4; kt++) {
        const int kg_ = kbase + kt * 16 + quad * 4;
        const int qg_ = qB + l16;
#pragma unroll
        for (int r = 0; r < 4; r++)
          if (kg_ + r > qg_) st[kt][1][r] = -INFINITY;
      }
    }

    // ---- online softmax (per-lane rows; quad-reduce via shfl_xor) ----
    float al2[2] = {1.f, 1.f};
#pragma unroll
    for (int q2 = 0; q2 < 2; q2++) {
      if (q2 == 0 && !actA) continue;
      float mx = -INFINITY;
#pragma unroll
      for (int kt = 0; kt < 4; kt++)
#pragma unroll
        for (int r = 0; r < 4; r++) mx = fmaxf(mx, st[kt][q2][r]);
      mx = fmaxf(mx, __shfl_xor(mx, 16, 64));
      mx = fmaxf(mx, __shfl_xor(mx, 32, 64));
      const float mnew = fmaxf(m_s[q2], mx);
      const float a = __expf(m_s[q2] - mnew);  // first chunk: exp(-inf)=0
      m_s[q2] = mnew;
      al2[q2] = a;
      float sum = 0.f;
#pragma unroll
      for (int kt = 0; kt < 4; kt++) {
        ushort4 pk_;
#pragma unroll
        for (int r = 0; r < 4; r++) {
          const float p = __expf(st[kt][q2][r] - mnew);
          sum += p;
          ((unsigned short*)&pk_)[r] = f2bf(p);
        }
        *(ushort4*)&Pw[w][(q2 * 16 + l16) * 72 + kt * 16 + quad * 4] = pk_;
      }
      sum += __shfl_xor(sum, 16, 64);
      sum += __shfl_xor(sum, 32, 64);
      l_s[q2] = l_s[q2] * a + sum;
    }

    // ---- O rescale by alpha (broadcast to C-layout rows) ----
#pragma unroll
    for (int mt = 0; mt < 2; mt++) {
      if (mt == 0 && !actA) continue;
#pragma unroll
      for (int r = 0; r < 4; r++) {
        const float ar = __shfl(al2[mt], quad * 4 + r, 16);
#pragma unroll
        for (int nd = 0; nd < 4; nd++) of_[mt][nd][r] *= ar;
      }
    }

    // ---- O += P·V ----
#pragma unroll
    for (int kk = 0; kk < 2; kk++) {
      bf16x8 pa0;
      if (actA) pa0 = *(const bf16x8*)&Pw[w][(l16) * 72 + kk * 32 + quad * 8];
      const bf16x8 pa1 =
          *(const bf16x8*)&Pw[w][(16 + l16) * 72 + kk * 32 + quad * 8];
#pragma unroll
      for (int nd = 0; nd < 4; nd++) {
        const int d = nd * 16 + l16;
        const bf16x8 vbf =
            *(const bf16x8*)&Vt[d * 72 + (((kk * 4 + quad) ^ (d >> 3)) & 7) * 8];
        if (actA)
          of_[0][nd] = __builtin_amdgcn_mfma_f32_16x16x32_bf16(pa0, vbf,
                                                               of_[0][nd], 0, 0, 0);
        of_[1][nd] = __builtin_amdgcn_mfma_f32_16x16x32_bf16(pa1, vbf,
                                                             of_[1][nd], 0, 0, 0);
      }
    }
  }

  // ---- normalize + write O (row q = quad*4+reg, col d = l16) ----
  const float li0 = 1.f / l_s[0], li1 = 1.f / l_s[1];
#pragma unroll
  for (int mt = 0; mt < 2; mt++) {
    const int qbase = (mt == 0) ? qA : qB;
#pragma unroll
    for (int r = 0; r < 4; r++) {
      const float lr = __shfl(mt == 0 ? li0 : li1, quad * 4 + r, 16);
      const size_t rowoff = (size_t)(b * NL + qbase + quad * 4 + r) * ND + h * NDH;
#pragma unroll
      for (int nd = 0; nd < 4; nd++)
        out[rowoff + nd * 16 + l16] = f2bf(of_[mt][nd][r] * lr);
    }
  }
}

// ---------------------------------------------------------------------------
// Residual add + LayerNorm (ddof=1, y=(x-mean)/(std+eps)*g + b). All f32.
// ---------------------------------------------------------------------------
__device__ __forceinline__ float block_sum256(float v, float* sbuf) {
#pragma unroll
  for (int off = 32; off > 0; off >>= 1) v += __shfl_down(v, off, 64);
  const int tid = threadIdx.x;
  if ((tid & 63) == 0) sbuf[tid >> 6] = v;
  __syncthreads();
  return sbuf[0] + sbuf[1] + sbuf[2] + sbuf[3];
}

template <bool WRITE_BF16>
__global__ __launch_bounds__(256, 4) void add_ln_kernel(
    const float* __restrict__ a, const float* __restrict__ res,
    const float* __restrict__ gam, const float* __restrict__ bet,
    float* __restrict__ of, unsigned short* __restrict__ ob) {
  const int row = blockIdx.x, tid = threadIdx.x;
  __shared__ float sbuf[4];
  const size_t base = (size_t)row * ND;
  float x[4];
#pragma unroll
  for (int e = 0; e < 4; e++) {
    const int idx = tid + 256 * e;
    x[e] = a[base + idx] + res[base + idx];
  }
  float s = x[0] + x[1] + x[2] + x[3];
  s = block_sum256(s, sbuf);
  const float mean = s * (1.f / (float)ND);
  float sq = 0.f;
#pragma unroll
  for (int e = 0; e < 4; e++) {
    const float d = x[e] - mean;
    sq += d * d;
  }
  __syncthreads();
  sq = block_sum256(sq, sbuf);
  const float inv = 1.f / (sqrtf(sq * (1.f / (float)(ND - 1))) + 1e-6f);
#pragma unroll
  for (int e = 0; e < 4; e++) {
    const int idx = tid + 256 * e;
    const float y = (x[e] - mean) * inv * gam[idx] + bet[idx];
    of[base + idx] = y;
    if (WRITE_BF16) ob[base + idx] = f2bf(y);
  }
}

// ---------------------------------------------------------------------------
extern "C" void kernel_launch(void* const* d_in, const int* in_sizes, int n_in,
                              void* d_out, int out_size, void* d_ws, size_t ws_size,
                              hipStream_t stream) {
  const float* x = (const float*)d_in[0];
  // d_in[1] = mask (int32) — exactly causal, handled analytically
  const float* Wqkv = (const float*)d_in[2];
  const float* bqkv = (const float*)d_in[3];
  const float* Wo = (const float*)d_in[4];
  const float* bo = (const float*)d_in[5];
  const float* ln1a = (const float*)d_in[6];
  const float* ln1b = (const float*)d_in[7];
  const float* W1 = (const float*)d_in[8];
  const float* b1 = (const float*)d_in[9];
  const float* W2 = (const float*)d_in[10];
  const float* b2 = (const float*)d_in[11];
  const float* ln2a = (const float*)d_in[12];
  const float* ln2b = (const float*)d_in[13];

  char* ws = (char*)d_ws;
  unsigned short* qkv = (unsigned short*)(ws);
  unsigned short* aout = (unsigned short*)(ws + 25165824);
  unsigned short* ffn1 = (unsigned short*)(ws);
  float* tmpf = (float*)(ws + 33554432);
  float* hf = (float*)(ws + 50331648);
  unsigned short* hb = (unsigned short*)(ws + 67108864);
  unsigned short* xb = (unsigned short*)(ws + 75497472);
  unsigned short* Wqkvb = (unsigned short*)(ws + 83886080);
  unsigned short* Wob = (unsigned short*)(ws + 90177536);
  unsigned short* W1b = (unsigned short*)(ws + 92274688);
  unsigned short* W2b = (unsigned short*)(ws + 100663296);

  const int M = NB * NL;  // 4096
  dim3 blk(256);

  cast_f32_bf16<<<dim3(M * ND / 4 / 256), blk, 0, stream>>>(x, xb, M * ND / 4);
  cast_f32_bf16<<<dim3(3 * ND * ND / 4 / 256), blk, 0, stream>>>(Wqkv, Wqkvb,
                                                                 3 * ND * ND / 4);
  cast_f32_bf16<<<dim3(ND * ND / 4 / 256), blk, 0, stream>>>(Wo, Wob, ND * ND / 4);
  cast_f32_bf16<<<dim3(NDFF * ND / 4 / 256), blk, 0, stream>>>(W1, W1b,
                                                               NDFF * ND / 4);
  cast_f32_bf16<<<dim3(ND * NDFF / 4 / 256), blk, 0, stream>>>(W2, W2b,
                                                               ND * NDFF / 4);

  gemm_bt<false, true><<<dim3(3 * ND / 128, M / 128), blk, 0, stream>>>(
      xb, Wqkvb, bqkv, qkv, nullptr, M, 3 * ND, ND);
  attn_mfma<<<dim3(NB * NH, NL / 128), blk, 0, stream>>>(qkv, aout);
  gemm_bt<false, false><<<dim3(ND / 128, M / 128), blk, 0, stream>>>(
      aout, Wob, bo, nullptr, tmpf, M, ND, ND);
  add_ln_kernel<true><<<dim3(M), blk, 0, stream>>>(tmpf, x, ln1a, ln1b, hf, hb);
  gemm_bt<true, true><<<dim3(NDFF / 128, M / 128), blk, 0, stream>>>(
      hb, W1b, b1, ffn1, nullptr, M, NDFF, ND);
  gemm_bt<false, false><<<dim3(ND / 128, M / 128), blk, 0, stream>>>(
      ffn1, W2b, b2, nullptr, tmpf, M, ND, NDFF);
  add_ln_kernel<false><<<dim3(M), blk, 0, stream>>>(tmpf, hf, ln2a, ln2b,
                                                    (float*)d_out, nullptr);
}

// Round 5
// 394.727 us; speedup vs baseline: 1.0739x; 1.0739x over previous
//
#include <hip/hip_runtime.h>
#include <cstdint>
#include <cstddef>

#define NB 2
#define NL 2048
#define ND 1024
#define NH 16
#define NDH 64
#define NDFF 4096

typedef __bf16 bf16_t;
typedef bf16_t bf16x8 __attribute__((ext_vector_type(8)));
typedef float f32x4 __attribute__((ext_vector_type(4)));

__device__ __forceinline__ float bf2f(unsigned short h) {
  union { unsigned u; float f; } c; c.u = ((unsigned)h) << 16; return c.f;
}
__device__ __forceinline__ unsigned short f2bf(float f) {
  union { float f; unsigned u; } c; c.f = f;
  return (unsigned short)((c.u + 0x7fffu + ((c.u >> 16) & 1u)) >> 16);
}

// async global->LDS, 16B per lane; lds base must be wave-uniform.
__device__ __forceinline__ void async_copy16(const void* g, void* l) {
  __builtin_amdgcn_global_load_lds(
      (const __attribute__((address_space(1))) void*)g,
      (__attribute__((address_space(3))) void*)l, 16, 0, 0);
}

// ---------------------------------------------------------------------------
// Fused f32 -> bf16 cast of x + all 4 weight matrices, one launch.
// Segment boundaries in vec4 units (hardcoded for this problem).
// ---------------------------------------------------------------------------
__global__ __launch_bounds__(256) void cast_all(
    const float* __restrict__ x, const float* __restrict__ wqkv,
    const float* __restrict__ wo, const float* __restrict__ w1,
    const float* __restrict__ w2, unsigned short* __restrict__ xb,
    unsigned short* __restrict__ wqkvb, unsigned short* __restrict__ wob,
    unsigned short* __restrict__ w1b, unsigned short* __restrict__ w2b) {
  const int i = blockIdx.x * 256 + threadIdx.x;
  const float* src;
  unsigned short* dst;
  int off;
  if (i < 1048576) { src = x; dst = xb; off = i; }                    // 4M elems
  else if (i < 1835008) { src = wqkv; dst = wqkvb; off = i - 1048576; }
  else if (i < 2097152) { src = wo; dst = wob; off = i - 1835008; }
  else if (i < 3145728) { src = w1; dst = w1b; off = i - 2097152; }
  else { src = w2; dst = w2b; off = i - 3145728; }
  const float4 v = ((const float4*)src)[off];
  ushort4 o;
  o.x = f2bf(v.x); o.y = f2bf(v.y); o.z = f2bf(v.z); o.w = f2bf(v.w);
  ((ushort4*)dst)[off] = o;
}

// ---------------------------------------------------------------------------
// GEMM: C[M,N] = A[M,K] @ W[N,K]^T + bias[N]  (A,W bf16; bias f32; C bf16/f32)
// BMx128 tile (BM=128 or 64), BK=32, 4 waves 2x2. Double-buffered LDS with
// global_load_lds width-16: stage tile k+1 right after the barrier that
// publishes tile k, compute tile k while loads fly. One barrier per K-iter.
// ---------------------------------------------------------------------------
template <int BM, bool RELU, bool OUT_BF16>
__global__ __launch_bounds__(256, 2) void gemm_bt(
    const unsigned short* __restrict__ A, const unsigned short* __restrict__ W,
    const float* __restrict__ bias, unsigned short* __restrict__ outb,
    float* __restrict__ outf, int M, int N, int K) {
  constexpr int MI = BM / 32;   // mfma m-tiles per wave (4 or 2)
  constexpr int ACP = BM / 64;  // A staging copies (2 or 1)
  const int tid = threadIdx.x;
  const int wave = tid >> 6, lane = tid & 63;
  const int quad = lane >> 4, l16 = lane & 15;
  const int wm = wave & 1, wn = wave >> 1;
  const int m0 = blockIdx.y * BM, n0 = blockIdx.x * 128;

  __shared__ __align__(16) unsigned short As[2][BM * 32];
  __shared__ __align__(16) unsigned short Bs[2][128 * 32];

  const int r0 = tid >> 2;       // 0..63
  const int kc = (tid & 3) * 8;  // 0,8,16,24
  const unsigned short* Ag[ACP];
#pragma unroll
  for (int i = 0; i < ACP; i++) Ag[i] = A + (size_t)(m0 + r0 + 64 * i) * K + kc;
  const unsigned short* Bg[2];
#pragma unroll
  for (int i = 0; i < 2; i++) Bg[i] = W + (size_t)(n0 + r0 + 64 * i) * K + kc;

  f32x4 acc[MI][4];
#pragma unroll
  for (int i = 0; i < MI; i++)
#pragma unroll
    for (int j = 0; j < 4; j++) acc[i][j] = (f32x4){0.f, 0.f, 0.f, 0.f};

  // stage tile (k-offset koff) into buffer bsel
  auto stage = [&](int koff, int bsel) {
#pragma unroll
    for (int i = 0; i < ACP; i++)
      async_copy16(Ag[i] + koff, &As[bsel][(i * 256 + wave * 64) * 8]);
#pragma unroll
    for (int i = 0; i < 2; i++)
      async_copy16(Bg[i] + koff, &Bs[bsel][(i * 256 + wave * 64) * 8]);
  };

  stage(0, 0);
  int buf = 0;
  for (int k0 = 0; k0 < K; k0 += 32) {
    __syncthreads();  // drains vmcnt: tile k ready in As/Bs[buf]; prior reads of buf^1 done
    if (k0 + 32 < K) stage(k0 + 32, buf ^ 1);  // overlap with compute below
    bf16x8 af[MI], bfr[4];
#pragma unroll
    for (int i = 0; i < MI; i++)
      af[i] =
          *(const bf16x8*)&As[buf][(wm * (MI * 16) + i * 16 + l16) * 32 + quad * 8];
#pragma unroll
    for (int j = 0; j < 4; j++)
      bfr[j] = *(const bf16x8*)&Bs[buf][(wn * 64 + j * 16 + l16) * 32 + quad * 8];
#pragma unroll
    for (int i = 0; i < MI; i++)
#pragma unroll
      for (int j = 0; j < 4; j++)
        acc[i][j] =
            __builtin_amdgcn_mfma_f32_16x16x32_bf16(af[i], bfr[j], acc[i][j], 0, 0, 0);
    buf ^= 1;
  }

  // epilogue: D[row=quad*4+reg][col=l16] per 16x16 tile
#pragma unroll
  for (int j = 0; j < 4; j++) {
    const int col = n0 + wn * 64 + j * 16 + l16;
    const float bj = bias[col];
#pragma unroll
    for (int i = 0; i < MI; i++) {
      const int rowb = m0 + wm * (MI * 16) + i * 16 + quad * 4;
#pragma unroll
      for (int r = 0; r < 4; r++) {
        float v = acc[i][j][r] + bj;
        if (RELU) v = v > 0.f ? v : 0.f;
        const size_t idx = (size_t)(rowb + r) * N + col;
        if (OUT_BF16) outb[idx] = f2bf(v);
        else outf[idx] = v;
      }
    }
  }
}

// ---------------------------------------------------------------------------
// MFMA flash attention, causal (round-3 verified version). qkv: [B*L][3*ND]
// bf16, row = [q | k | v]. Block = 4 waves, 128 q-rows (wave w: 32 rows).
// S^T = K·Q^T (per-lane softmax stats). Grid: x=bh, y -> qt=15-y.
// ---------------------------------------------------------------------------
__global__ __launch_bounds__(256, 2) void attn_mfma(
    const unsigned short* __restrict__ qkv, unsigned short* __restrict__ out) {
  const int tid = threadIdx.x;
  const int w = tid >> 6, lane = tid & 63;
  const int quad = lane >> 4, l16 = lane & 15;
  const int bh = blockIdx.x;
  const int b = bh >> 4, h = bh & 15;
  const int qt = 15 - blockIdx.y;
  const int q0 = qt * 128;
  const int qw = q0 + w * 32;  // wave's first q row

  __shared__ __align__(16) unsigned short Ks[64 * 72];     // [k][d]
  __shared__ __align__(16) unsigned short Vt[64 * 72];     // [d][k-swizzled]
  __shared__ __align__(16) unsigned short Pw[4][32 * 72];  // per-wave P [q][k]

  // Q B-frags (x0.125 folded, exact): qb[q2][kd]
  bf16x8 qb[2][2];
#pragma unroll
  for (int q2 = 0; q2 < 2; q2++)
#pragma unroll
    for (int kd = 0; kd < 2; kd++) {
      const unsigned short* qp = qkv +
          (size_t)(b * NL + qw + q2 * 16 + l16) * (3 * ND) + h * NDH + kd * 32 + quad * 8;
      union { uint4 u; unsigned short s[8]; bf16x8 v; } qu;
      qu.u = *(const uint4*)qp;
#pragma unroll
      for (int e = 0; e < 8; e++) qu.s[e] = f2bf(bf2f(qu.s[e]) * 0.125f);
      qb[q2][kd] = qu.v;
    }

  float m_s[2] = {-INFINITY, -INFINITY};
  float l_s[2] = {0.f, 0.f};
  f32x4 of_[2][4];
#pragma unroll
  for (int mt = 0; mt < 2; mt++)
#pragma unroll
    for (int nd = 0; nd < 4; nd++) of_[mt][nd] = (f32x4){0.f, 0.f, 0.f, 0.f};

  const int nch = 2 * (qt + 1);
  for (int c = 0; c < nch; c++) {
    const int kbase = c * 64;
    __syncthreads();  // prior chunk's Ks/Vt reads complete
#pragma unroll
    for (int p = 0; p < 2; p++) {
      const int kk = p * 32 + (tid >> 3);
      const int d0 = (tid & 7) * 8;
      const unsigned short* gk =
          qkv + (size_t)(b * NL + kbase + kk) * (3 * ND) + ND + h * NDH + d0;
      uint4 ku = *(const uint4*)gk;
      uint4 vu = *(const uint4*)(gk + ND);
      *(uint4*)&Ks[kk * 72 + d0] = ku;
      const unsigned short* pv = (const unsigned short*)&vu;
      const int kg = kk >> 3, kr = kk & 7;
#pragma unroll
      for (int e = 0; e < 8; e++) {
        const int d = d0 + e;
        Vt[d * 72 + ((kg ^ (d >> 3)) & 7) * 8 + kr] = pv[e];
      }
    }
    __syncthreads();

    if (kbase <= qw + 31) {  // wave-uniform: chunk has unmasked work
      f32x4 st[4][2];
#pragma unroll
      for (int kt = 0; kt < 4; kt++)
#pragma unroll
        for (int q2 = 0; q2 < 2; q2++) st[kt][q2] = (f32x4){0.f, 0.f, 0.f, 0.f};
#pragma unroll
      for (int kd = 0; kd < 2; kd++)
#pragma unroll
        for (int kt = 0; kt < 4; kt++) {
          const bf16x8 kaf =
              *(const bf16x8*)&Ks[(kt * 16 + l16) * 72 + kd * 32 + quad * 8];
          st[kt][0] = __builtin_amdgcn_mfma_f32_16x16x32_bf16(kaf, qb[0][kd],
                                                              st[kt][0], 0, 0, 0);
          st[kt][1] = __builtin_amdgcn_mfma_f32_16x16x32_bf16(kaf, qb[1][kd],
                                                              st[kt][1], 0, 0, 0);
        }

      if (kbase + 63 > qw) {
#pragma unroll
        for (int kt = 0; kt < 4; kt++) {
          const int kg_ = kbase + kt * 16 + quad * 4;
#pragma unroll
          for (int q2 = 0; q2 < 2; q2++) {
            const int qg_ = qw + q2 * 16 + l16;
#pragma unroll
            for (int r = 0; r < 4; r++)
              if (kg_ + r > qg_) st[kt][q2][r] = -INFINITY;
          }
        }
      }

      float al2[2];
#pragma unroll
      for (int q2 = 0; q2 < 2; q2++) {
        float mx = -INFINITY;
#pragma unroll
        for (int kt = 0; kt < 4; kt++)
#pragma unroll
          for (int r = 0; r < 4; r++) mx = fmaxf(mx, st[kt][q2][r]);
        mx = fmaxf(mx, __shfl_xor(mx, 16, 64));
        mx = fmaxf(mx, __shfl_xor(mx, 32, 64));
        const float mnew = fmaxf(m_s[q2], mx);
        const float a = __expf(m_s[q2] - mnew);
        m_s[q2] = mnew;
        al2[q2] = a;
        float sum = 0.f;
#pragma unroll
        for (int kt = 0; kt < 4; kt++) {
          ushort4 pk_;
#pragma unroll
          for (int r = 0; r < 4; r++) {
            const float p = __expf(st[kt][q2][r] - mnew);
            sum += p;
            ((unsigned short*)&pk_)[r] = f2bf(p);
          }
          *(ushort4*)&Pw[w][(q2 * 16 + l16) * 72 + kt * 16 + quad * 4] = pk_;
        }
        sum += __shfl_xor(sum, 16, 64);
        sum += __shfl_xor(sum, 32, 64);
        l_s[q2] = l_s[q2] * a + sum;
      }

      float ar[2][4];
#pragma unroll
      for (int mt = 0; mt < 2; mt++)
#pragma unroll
        for (int r = 0; r < 4; r++)
          ar[mt][r] = __shfl(al2[mt], quad * 4 + r, 16);
#pragma unroll
      for (int mt = 0; mt < 2; mt++)
#pragma unroll
        for (int nd = 0; nd < 4; nd++)
#pragma unroll
          for (int r = 0; r < 4; r++) of_[mt][nd][r] *= ar[mt][r];

#pragma unroll
      for (int kk = 0; kk < 2; kk++) {
        const bf16x8 pa0 = *(const bf16x8*)&Pw[w][(l16) * 72 + kk * 32 + quad * 8];
        const bf16x8 pa1 =
            *(const bf16x8*)&Pw[w][(16 + l16) * 72 + kk * 32 + quad * 8];
#pragma unroll
        for (int nd = 0; nd < 4; nd++) {
          const int d = nd * 16 + l16;
          const bf16x8 vbf =
              *(const bf16x8*)&Vt[d * 72 + (((kk * 4 + quad) ^ (d >> 3)) & 7) * 8];
          of_[0][nd] = __builtin_amdgcn_mfma_f32_16x16x32_bf16(pa0, vbf,
                                                               of_[0][nd], 0, 0, 0);
          of_[1][nd] = __builtin_amdgcn_mfma_f32_16x16x32_bf16(pa1, vbf,
                                                               of_[1][nd], 0, 0, 0);
        }
      }
    }
  }

  const float li0 = 1.f / l_s[0], li1 = 1.f / l_s[1];
#pragma unroll
  for (int mt = 0; mt < 2; mt++) {
#pragma unroll
    for (int r = 0; r < 4; r++) {
      const float lr = __shfl(mt == 0 ? li0 : li1, quad * 4 + r, 16);
      const size_t rowoff =
          (size_t)(b * NL + qw + mt * 16 + quad * 4 + r) * ND + h * NDH;
#pragma unroll
      for (int nd = 0; nd < 4; nd++)
        out[rowoff + nd * 16 + l16] = f2bf(of_[mt][nd][r] * lr);
    }
  }
}

// ---------------------------------------------------------------------------
// Residual add + LayerNorm (ddof=1, y=(x-mean)/(std+eps)*g + b). All f32.
// ---------------------------------------------------------------------------
__device__ __forceinline__ float block_sum256(float v, float* sbuf) {
#pragma unroll
  for (int off = 32; off > 0; off >>= 1) v += __shfl_down(v, off, 64);
  const int tid = threadIdx.x;
  if ((tid & 63) == 0) sbuf[tid >> 6] = v;
  __syncthreads();
  return sbuf[0] + sbuf[1] + sbuf[2] + sbuf[3];
}

template <bool WRITE_BF16>
__global__ __launch_bounds__(256, 4) void add_ln_kernel(
    const float* __restrict__ a, const float* __restrict__ res,
    const float* __restrict__ gam, const float* __restrict__ bet,
    float* __restrict__ of, unsigned short* __restrict__ ob) {
  const int row = blockIdx.x, tid = threadIdx.x;
  __shared__ float sbuf[4];
  const size_t base = (size_t)row * ND;
  float x[4];
#pragma unroll
  for (int e = 0; e < 4; e++) {
    const int idx = tid + 256 * e;
    x[e] = a[base + idx] + res[base + idx];
  }
  float s = x[0] + x[1] + x[2] + x[3];
  s = block_sum256(s, sbuf);
  const float mean = s * (1.f / (float)ND);
  float sq = 0.f;
#pragma unroll
  for (int e = 0; e < 4; e++) {
    const float d = x[e] - mean;
    sq += d * d;
  }
  __syncthreads();
  sq = block_sum256(sq, sbuf);
  const float inv = 1.f / (sqrtf(sq * (1.f / (float)(ND - 1))) + 1e-6f);
#pragma unroll
  for (int e = 0; e < 4; e++) {
    const int idx = tid + 256 * e;
    const float y = (x[e] - mean) * inv * gam[idx] + bet[idx];
    of[base + idx] = y;
    if (WRITE_BF16) ob[base + idx] = f2bf(y);
  }
}

// ---------------------------------------------------------------------------
extern "C" void kernel_launch(void* const* d_in, const int* in_sizes, int n_in,
                              void* d_out, int out_size, void* d_ws, size_t ws_size,
                              hipStream_t stream) {
  const float* x = (const float*)d_in[0];
  // d_in[1] = mask (int32) — exactly causal, handled analytically
  const float* Wqkv = (const float*)d_in[2];
  const float* bqkv = (const float*)d_in[3];
  const float* Wo = (const float*)d_in[4];
  const float* bo = (const float*)d_in[5];
  const float* ln1a = (const float*)d_in[6];
  const float* ln1b = (const float*)d_in[7];
  const float* W1 = (const float*)d_in[8];
  const float* b1 = (const float*)d_in[9];
  const float* W2 = (const float*)d_in[10];
  const float* b2 = (const float*)d_in[11];
  const float* ln2a = (const float*)d_in[12];
  const float* ln2b = (const float*)d_in[13];

  char* ws = (char*)d_ws;
  unsigned short* qkv = (unsigned short*)(ws);
  unsigned short* aout = (unsigned short*)(ws + 25165824);
  unsigned short* ffn1 = (unsigned short*)(ws);
  float* tmpf = (float*)(ws + 33554432);
  float* hf = (float*)(ws + 50331648);
  unsigned short* hb = (unsigned short*)(ws + 67108864);
  unsigned short* xb = (unsigned short*)(ws + 75497472);
  unsigned short* Wqkvb = (unsigned short*)(ws + 83886080);
  unsigned short* Wob = (unsigned short*)(ws + 90177536);
  unsigned short* W1b = (unsigned short*)(ws + 92274688);
  unsigned short* W2b = (unsigned short*)(ws + 100663296);

  const int M = NB * NL;  // 4096
  dim3 blk(256);

  // 0) all f32->bf16 casts in one launch (4M vec4s -> 16384 blocks)
  cast_all<<<dim3(16384), blk, 0, stream>>>(x, Wqkv, Wo, W1, W2, xb, Wqkvb, Wob,
                                            W1b, W2b);

  // 1) qkv = x @ Wqkv^T + bqkv -> bf16
  gemm_bt<128, false, true><<<dim3(3 * ND / 128, M / 128), blk, 0, stream>>>(
      xb, Wqkvb, bqkv, qkv, nullptr, M, 3 * ND, ND);
  // 2) attention -> aout bf16
  attn_mfma<<<dim3(NB * NH, NL / 128), blk, 0, stream>>>(qkv, aout);
  // 3) proj = aout @ Wo^T + bo -> f32  (BM=64: 512 blocks, 2/CU)
  gemm_bt<64, false, false><<<dim3(ND / 128, M / 64), blk, 0, stream>>>(
      aout, Wob, bo, nullptr, tmpf, M, ND, ND);
  // 4) h = LN(x + proj) -> hf (f32) + hb (bf16)
  add_ln_kernel<true><<<dim3(M), blk, 0, stream>>>(tmpf, x, ln1a, ln1b, hf, hb);
  // 5) ffn1 = relu(h @ W1^T + b1) -> bf16
  gemm_bt<128, true, true><<<dim3(NDFF / 128, M / 128), blk, 0, stream>>>(
      hb, W1b, b1, ffn1, nullptr, M, NDFF, ND);
  // 6) ffn2 = ffn1 @ W2^T + b2 -> f32  (BM=64: 512 blocks, 2/CU)
  gemm_bt<64, false, false><<<dim3(ND / 128, M / 64), blk, 0, stream>>>(
      ffn1, W2b, b2, nullptr, tmpf, M, ND, NDFF);
  // 7) out = LN(h + ffn2) -> f32 d_out
  add_ln_kernel<false><<<dim3(M), blk, 0, stream>>>(tmpf, hf, ln2a, ln2b,
                                                    (float*)d_out, nullptr);
}

// Round 6
// 386.478 us; speedup vs baseline: 1.0968x; 1.0213x over previous
//
#include <hip/hip_runtime.h>
#include <cstdint>
#include <cstddef>

#define NB 2
#define NL 2048
#define ND 1024
#define NH 16
#define NDH 64
#define NDFF 4096

typedef __bf16 bf16_t;
typedef bf16_t bf16x8 __attribute__((ext_vector_type(8)));
typedef float f32x4 __attribute__((ext_vector_type(4)));

__device__ __forceinline__ float bf2f(unsigned short h) {
  union { unsigned u; float f; } c; c.u = ((unsigned)h) << 16; return c.f;
}
__device__ __forceinline__ unsigned short f2bf(float f) {
  union { float f; unsigned u; } c; c.f = f;
  return (unsigned short)((c.u + 0x7fffu + ((c.u >> 16) & 1u)) >> 16);
}

// async global->LDS, 16B per lane; lds base must be wave-uniform.
__device__ __forceinline__ void async_copy16(const void* g, void* l) {
  __builtin_amdgcn_global_load_lds(
      (const __attribute__((address_space(1))) void*)g,
      (__attribute__((address_space(3))) void*)l, 16, 0, 0);
}

// ---------------------------------------------------------------------------
// Fused f32 -> bf16 cast of x + all 4 weight matrices, one launch.
// ---------------------------------------------------------------------------
__global__ __launch_bounds__(256) void cast_all(
    const float* __restrict__ x, const float* __restrict__ wqkv,
    const float* __restrict__ wo, const float* __restrict__ w1,
    const float* __restrict__ w2, unsigned short* __restrict__ xb,
    unsigned short* __restrict__ wqkvb, unsigned short* __restrict__ wob,
    unsigned short* __restrict__ w1b, unsigned short* __restrict__ w2b) {
  const int i = blockIdx.x * 256 + threadIdx.x;
  const float* src;
  unsigned short* dst;
  int off;
  if (i < 1048576) { src = x; dst = xb; off = i; }  // 4M elems (vec4)
  else if (i < 1835008) { src = wqkv; dst = wqkvb; off = i - 1048576; }
  else if (i < 2097152) { src = wo; dst = wob; off = i - 1835008; }
  else if (i < 3145728) { src = w1; dst = w1b; off = i - 2097152; }
  else { src = w2; dst = w2b; off = i - 3145728; }
  const float4 v = ((const float4*)src)[off];
  ushort4 o;
  o.x = f2bf(v.x); o.y = f2bf(v.y); o.z = f2bf(v.z); o.w = f2bf(v.w);
  ((ushort4*)dst)[off] = o;
}

// ---------------------------------------------------------------------------
// GEMM: C[M,N] = A[M,K] @ W[N,K]^T (+ bias[N]) (A,W bf16; C bf16/f32)
// BMx128 tile, BK=32, 4 waves 2x2. Double-buffered LDS, global_load_lds
// width-16, one barrier per K-iter. Split-K via gridDim.z: block z covers
// K-range [z*K/gz,(z+1)*K/gz), writes f32 partial at outf + z*M*N; partials
// are summed downstream in the LN kernel (no extra reduce dispatch).
// ---------------------------------------------------------------------------
template <int BM, bool RELU, bool OUT_BF16, bool BIAS>
__global__ __launch_bounds__(256, 2) void gemm_bt(
    const unsigned short* __restrict__ A, const unsigned short* __restrict__ W,
    const float* __restrict__ bias, unsigned short* __restrict__ outb,
    float* __restrict__ outf, int M, int N, int K) {
  constexpr int MI = BM / 32;   // mfma m-tiles per wave (4 or 2)
  constexpr int ACP = BM / 64;  // A staging copies (2 or 1)
  const int tid = threadIdx.x;
  const int wave = tid >> 6, lane = tid & 63;
  const int quad = lane >> 4, l16 = lane & 15;
  const int wm = wave & 1, wn = wave >> 1;
  const int m0 = blockIdx.y * BM, n0 = blockIdx.x * 128;
  const int kz = blockIdx.z;
  const int Kh = K / gridDim.z;  // this block's K extent
  const int kof = kz * Kh;       // this block's K start

  __shared__ __align__(16) unsigned short As[2][BM * 32];
  __shared__ __align__(16) unsigned short Bs[2][128 * 32];

  const int r0 = tid >> 2;       // 0..63
  const int kc = (tid & 3) * 8;  // 0,8,16,24
  const unsigned short* Ag[ACP];
#pragma unroll
  for (int i = 0; i < ACP; i++)
    Ag[i] = A + (size_t)(m0 + r0 + 64 * i) * K + kof + kc;
  const unsigned short* Bg[2];
#pragma unroll
  for (int i = 0; i < 2; i++)
    Bg[i] = W + (size_t)(n0 + r0 + 64 * i) * K + kof + kc;

  f32x4 acc[MI][4];
#pragma unroll
  for (int i = 0; i < MI; i++)
#pragma unroll
    for (int j = 0; j < 4; j++) acc[i][j] = (f32x4){0.f, 0.f, 0.f, 0.f};

  auto stage = [&](int koff, int bsel) {
#pragma unroll
    for (int i = 0; i < ACP; i++)
      async_copy16(Ag[i] + koff, &As[bsel][(i * 256 + wave * 64) * 8]);
#pragma unroll
    for (int i = 0; i < 2; i++)
      async_copy16(Bg[i] + koff, &Bs[bsel][(i * 256 + wave * 64) * 8]);
  };

  stage(0, 0);
  int buf = 0;
  for (int k0 = 0; k0 < Kh; k0 += 32) {
    __syncthreads();  // tile k ready in buf; prior reads of buf^1 done
    if (k0 + 32 < Kh) stage(k0 + 32, buf ^ 1);  // overlap with compute
    bf16x8 af[MI], bfr[4];
#pragma unroll
    for (int i = 0; i < MI; i++)
      af[i] =
          *(const bf16x8*)&As[buf][(wm * (MI * 16) + i * 16 + l16) * 32 + quad * 8];
#pragma unroll
    for (int j = 0; j < 4; j++)
      bfr[j] = *(const bf16x8*)&Bs[buf][(wn * 64 + j * 16 + l16) * 32 + quad * 8];
#pragma unroll
    for (int i = 0; i < MI; i++)
#pragma unroll
      for (int j = 0; j < 4; j++)
        acc[i][j] =
            __builtin_amdgcn_mfma_f32_16x16x32_bf16(af[i], bfr[j], acc[i][j], 0, 0, 0);
    buf ^= 1;
  }

  float* outp = outf + (size_t)kz * M * N;  // partial slot (split-K)
#pragma unroll
  for (int j = 0; j < 4; j++) {
    const int col = n0 + wn * 64 + j * 16 + l16;
    const float bj = BIAS ? bias[col] : 0.f;
#pragma unroll
    for (int i = 0; i < MI; i++) {
      const int rowb = m0 + wm * (MI * 16) + i * 16 + quad * 4;
#pragma unroll
      for (int r = 0; r < 4; r++) {
        float v = acc[i][j][r] + bj;
        if (RELU) v = v > 0.f ? v : 0.f;
        const size_t idx = (size_t)(rowb + r) * N + col;
        if (OUT_BF16) outb[idx] = f2bf(v);
        else outp[idx] = v;
      }
    }
  }
}

// ---------------------------------------------------------------------------
// MFMA flash attention, causal (round-3 core + balanced qt pairing).
// qkv: [B*L][3*ND] bf16, row = [q | k | v]. Block = 4 waves, 128 q-rows
// (wave w: rows qw..qw+31). S^T = K·Q^T (per-lane softmax stats).
// Grid (32,16); qt = y<8 ? 15-2y : 2(y-8) so pairs (i, i+256) sum to 15.
// ---------------------------------------------------------------------------
__global__ __launch_bounds__(256, 2) void attn_mfma(
    const unsigned short* __restrict__ qkv, unsigned short* __restrict__ out) {
  const int tid = threadIdx.x;
  const int w = tid >> 6, lane = tid & 63;
  const int quad = lane >> 4, l16 = lane & 15;
  const int bh = blockIdx.x;
  const int b = bh >> 4, h = bh & 15;
  const int y = blockIdx.y;
  const int qt = (y < 8) ? (15 - 2 * y) : (2 * (y - 8));
  const int q0 = qt * 128;
  const int qw = q0 + w * 32;  // wave's first q row

  __shared__ __align__(16) unsigned short Ks[64 * 72];     // [k][d]
  __shared__ __align__(16) unsigned short Vt[64 * 72];     // [d][k-swizzled]
  __shared__ __align__(16) unsigned short Pw[4][32 * 72];  // per-wave P [q][k]

  bf16x8 qb[2][2];
#pragma unroll
  for (int q2 = 0; q2 < 2; q2++)
#pragma unroll
    for (int kd = 0; kd < 2; kd++) {
      const unsigned short* qp = qkv +
          (size_t)(b * NL + qw + q2 * 16 + l16) * (3 * ND) + h * NDH + kd * 32 + quad * 8;
      union { uint4 u; unsigned short s[8]; bf16x8 v; } qu;
      qu.u = *(const uint4*)qp;
#pragma unroll
      for (int e = 0; e < 8; e++) qu.s[e] = f2bf(bf2f(qu.s[e]) * 0.125f);
      qb[q2][kd] = qu.v;
    }

  float m_s[2] = {-INFINITY, -INFINITY};
  float l_s[2] = {0.f, 0.f};
  f32x4 of_[2][4];
#pragma unroll
  for (int mt = 0; mt < 2; mt++)
#pragma unroll
    for (int nd = 0; nd < 4; nd++) of_[mt][nd] = (f32x4){0.f, 0.f, 0.f, 0.f};

  const int nch = 2 * (qt + 1);
  for (int c = 0; c < nch; c++) {
    const int kbase = c * 64;
    __syncthreads();  // prior chunk's Ks/Vt reads complete
#pragma unroll
    for (int p = 0; p < 2; p++) {
      const int kk = p * 32 + (tid >> 3);
      const int d0 = (tid & 7) * 8;
      const unsigned short* gk =
          qkv + (size_t)(b * NL + kbase + kk) * (3 * ND) + ND + h * NDH + d0;
      uint4 ku = *(const uint4*)gk;
      uint4 vu = *(const uint4*)(gk + ND);
      *(uint4*)&Ks[kk * 72 + d0] = ku;
      const unsigned short* pv = (const unsigned short*)&vu;
      const int kg = kk >> 3, kr = kk & 7;
#pragma unroll
      for (int e = 0; e < 8; e++) {
        const int d = d0 + e;
        Vt[d * 72 + ((kg ^ (d >> 3)) & 7) * 8 + kr] = pv[e];
      }
    }
    __syncthreads();

    if (kbase <= qw + 31) {  // wave-uniform: chunk has unmasked work
      f32x4 st[4][2];
#pragma unroll
      for (int kt = 0; kt < 4; kt++)
#pragma unroll
        for (int q2 = 0; q2 < 2; q2++) st[kt][q2] = (f32x4){0.f, 0.f, 0.f, 0.f};
#pragma unroll
      for (int kd = 0; kd < 2; kd++)
#pragma unroll
        for (int kt = 0; kt < 4; kt++) {
          const bf16x8 kaf =
              *(const bf16x8*)&Ks[(kt * 16 + l16) * 72 + kd * 32 + quad * 8];
          st[kt][0] = __builtin_amdgcn_mfma_f32_16x16x32_bf16(kaf, qb[0][kd],
                                                              st[kt][0], 0, 0, 0);
          st[kt][1] = __builtin_amdgcn_mfma_f32_16x16x32_bf16(kaf, qb[1][kd],
                                                              st[kt][1], 0, 0, 0);
        }

      if (kbase + 63 > qw) {
#pragma unroll
        for (int kt = 0; kt < 4; kt++) {
          const int kg_ = kbase + kt * 16 + quad * 4;
#pragma unroll
          for (int q2 = 0; q2 < 2; q2++) {
            const int qg_ = qw + q2 * 16 + l16;
#pragma unroll
            for (int r = 0; r < 4; r++)
              if (kg_ + r > qg_) st[kt][q2][r] = -INFINITY;
          }
        }
      }

      float al2[2];
#pragma unroll
      for (int q2 = 0; q2 < 2; q2++) {
        float mx = -INFINITY;
#pragma unroll
        for (int kt = 0; kt < 4; kt++)
#pragma unroll
          for (int r = 0; r < 4; r++) mx = fmaxf(mx, st[kt][q2][r]);
        mx = fmaxf(mx, __shfl_xor(mx, 16, 64));
        mx = fmaxf(mx, __shfl_xor(mx, 32, 64));
        const float mnew = fmaxf(m_s[q2], mx);
        const float a = __expf(m_s[q2] - mnew);
        m_s[q2] = mnew;
        al2[q2] = a;
        float sum = 0.f;
#pragma unroll
        for (int kt = 0; kt < 4; kt++) {
          ushort4 pk_;
#pragma unroll
          for (int r = 0; r < 4; r++) {
            const float p = __expf(st[kt][q2][r] - mnew);
            sum += p;
            ((unsigned short*)&pk_)[r] = f2bf(p);
          }
          *(ushort4*)&Pw[w][(q2 * 16 + l16) * 72 + kt * 16 + quad * 4] = pk_;
        }
        sum += __shfl_xor(sum, 16, 64);
        sum += __shfl_xor(sum, 32, 64);
        l_s[q2] = l_s[q2] * a + sum;
      }

      float ar[2][4];
#pragma unroll
      for (int mt = 0; mt < 2; mt++)
#pragma unroll
        for (int r = 0; r < 4; r++)
          ar[mt][r] = __shfl(al2[mt], quad * 4 + r, 16);
#pragma unroll
      for (int mt = 0; mt < 2; mt++)
#pragma unroll
        for (int nd = 0; nd < 4; nd++)
#pragma unroll
          for (int r = 0; r < 4; r++) of_[mt][nd][r] *= ar[mt][r];

#pragma unroll
      for (int kk = 0; kk < 2; kk++) {
        const bf16x8 pa0 = *(const bf16x8*)&Pw[w][(l16) * 72 + kk * 32 + quad * 8];
        const bf16x8 pa1 =
            *(const bf16x8*)&Pw[w][(16 + l16) * 72 + kk * 32 + quad * 8];
#pragma unroll
        for (int nd = 0; nd < 4; nd++) {
          const int d = nd * 16 + l16;
          const bf16x8 vbf =
              *(const bf16x8*)&Vt[d * 72 + (((kk * 4 + quad) ^ (d >> 3)) & 7) * 8];
          of_[0][nd] = __builtin_amdgcn_mfma_f32_16x16x32_bf16(pa0, vbf,
                                                               of_[0][nd], 0, 0, 0);
          of_[1][nd] = __builtin_amdgcn_mfma_f32_16x16x32_bf16(pa1, vbf,
                                                               of_[1][nd], 0, 0, 0);
        }
      }
    }
  }

  const float li0 = 1.f / l_s[0], li1 = 1.f / l_s[1];
#pragma unroll
  for (int mt = 0; mt < 2; mt++) {
#pragma unroll
    for (int r = 0; r < 4; r++) {
      const float lr = __shfl(mt == 0 ? li0 : li1, quad * 4 + r, 16);
      const size_t rowoff =
          (size_t)(b * NL + qw + mt * 16 + quad * 4 + r) * ND + h * NDH;
#pragma unroll
      for (int nd = 0; nd < 4; nd++)
        out[rowoff + nd * 16 + l16] = f2bf(of_[mt][nd][r] * lr);
    }
  }
}

// ---------------------------------------------------------------------------
// (p0 + p1 + bias + res) -> LayerNorm (ddof=1). All f32; optional bf16 copy.
// One block (256 thr) per row of 1024.
// ---------------------------------------------------------------------------
__device__ __forceinline__ float block_sum256(float v, float* sbuf) {
#pragma unroll
  for (int off = 32; off > 0; off >>= 1) v += __shfl_down(v, off, 64);
  const int tid = threadIdx.x;
  if ((tid & 63) == 0) sbuf[tid >> 6] = v;
  __syncthreads();
  return sbuf[0] + sbuf[1] + sbuf[2] + sbuf[3];
}

template <bool WRITE_BF16>
__global__ __launch_bounds__(256, 4) void add_ln_kernel(
    const float* __restrict__ p0, const float* __restrict__ p1,
    const float* __restrict__ bias, const float* __restrict__ res,
    const float* __restrict__ gam, const float* __restrict__ bet,
    float* __restrict__ of, unsigned short* __restrict__ ob) {
  const int row = blockIdx.x, tid = threadIdx.x;
  __shared__ float sbuf[4];
  const size_t base = (size_t)row * ND;
  float x[4];
#pragma unroll
  for (int e = 0; e < 4; e++) {
    const int idx = tid + 256 * e;
    x[e] = p0[base + idx] + p1[base + idx] + bias[idx] + res[base + idx];
  }
  float s = x[0] + x[1] + x[2] + x[3];
  s = block_sum256(s, sbuf);
  const float mean = s * (1.f / (float)ND);
  float sq = 0.f;
#pragma unroll
  for (int e = 0; e < 4; e++) {
    const float d = x[e] - mean;
    sq += d * d;
  }
  __syncthreads();
  sq = block_sum256(sq, sbuf);
  const float inv = 1.f / (sqrtf(sq * (1.f / (float)(ND - 1))) + 1e-6f);
#pragma unroll
  for (int e = 0; e < 4; e++) {
    const int idx = tid + 256 * e;
    const float y = (x[e] - mean) * inv * gam[idx] + bet[idx];
    of[base + idx] = y;
    if (WRITE_BF16) ob[base + idx] = f2bf(y);
  }
}

// ---------------------------------------------------------------------------
extern "C" void kernel_launch(void* const* d_in, const int* in_sizes, int n_in,
                              void* d_out, int out_size, void* d_ws, size_t ws_size,
                              hipStream_t stream) {
  const float* x = (const float*)d_in[0];
  // d_in[1] = mask (int32) — exactly causal, handled analytically
  const float* Wqkv = (const float*)d_in[2];
  const float* bqkv = (const float*)d_in[3];
  const float* Wo = (const float*)d_in[4];
  const float* bo = (const float*)d_in[5];
  const float* ln1a = (const float*)d_in[6];
  const float* ln1b = (const float*)d_in[7];
  const float* W1 = (const float*)d_in[8];
  const float* b1 = (const float*)d_in[9];
  const float* W2 = (const float*)d_in[10];
  const float* b2 = (const float*)d_in[11];
  const float* ln2a = (const float*)d_in[12];
  const float* ln2b = (const float*)d_in[13];

  // workspace layout (MiB); peak 104 MiB (same as previously proven):
  //  [0,24)   qkv bf16        (live steps 1-2)
  //  [0,32)   ffn1 bf16       (live steps 5-6; after qkv dead)
  //  [24,32)  aout bf16       (live steps 2-3)
  //  [32,64)  tmpf f32 x2 partials, CONTIGUOUS (Wo: steps 3-4; W2: 6-7)
  //  [64,80)  hf f32          (live steps 4-7)
  //  [80,88)  hb bf16         (live steps 4-5; Wqkvb/Wob dead by then)
  //  [88,96)  xb bf16         (live steps 0-1)
  //  [88,94)  Wqkvb... CONFLICT with xb (both live step 0-1)!
  // -> weights go after xb: Wqkvb [96,102), Wob [102,104) -> hb cannot
  //    overlap them until step 4 (Wob dead after step 3: hb written step 4,
  //    OK) but Wqkvb region [96,102) + W1b... Final packing below keeps
  //    every region single-writer-then-reader; peak = 104 MiB:
  //    qkv/ffn1 [0,32) | tmpf [32,64) | hf [64,80) | xb [80,88) |
  //    Wqkvb [88,94) | Wob [94,96) | W1b [96,104)... W2b needs 8 more ->
  //    W2b overlays [80,88) is ILLEGAL (xb live 0-1, W2b written step 0).
  //    So: W2b [104,112) — peak 112 MiB (+8 over proven; accepted) and
  //    hb overlays Wqkvb+Wob [88,96) (both dead after step 3; hb step 4-5).
  char* ws = (char*)d_ws;
  unsigned short* qkv = (unsigned short*)(ws);
  unsigned short* ffn1 = (unsigned short*)(ws);
  unsigned short* aout = (unsigned short*)(ws + 25165824);
  float* tmpf = (float*)(ws + 33554432);        // [32,64): two 16-MiB partials
  float* hf = (float*)(ws + 67108864);          // [64,80)
  unsigned short* xb = (unsigned short*)(ws + 83886080);     // [80,88)
  unsigned short* Wqkvb = (unsigned short*)(ws + 92274688);  // [88,94)
  unsigned short* Wob = (unsigned short*)(ws + 98566144);    // [94,96)
  unsigned short* hb = (unsigned short*)(ws + 92274688);     // [88,96) step 4+
  unsigned short* W1b = (unsigned short*)(ws + 100663296);   // [96,104)
  unsigned short* W2b = (unsigned short*)(ws + 109051904);   // [104,112)

  const int M = NB * NL;  // 4096
  dim3 blk(256);

  // 0) all f32->bf16 casts in one launch
  cast_all<<<dim3(16384), blk, 0, stream>>>(x, Wqkv, Wo, W1, W2, xb, Wqkvb, Wob,
                                            W1b, W2b);
  // 1) qkv = x @ Wqkv^T + bqkv -> bf16
  gemm_bt<128, false, true, true><<<dim3(3 * ND / 128, M / 128), blk, 0, stream>>>(
      xb, Wqkvb, bqkv, qkv, nullptr, M, 3 * ND, ND);
  // 2) attention -> aout bf16
  attn_mfma<<<dim3(NB * NH, NL / 128), blk, 0, stream>>>(qkv, aout);
  // 3) Wo partials (split-K x2 -> 1024 blocks, 4/CU): tmpf + z*M*N
  gemm_bt<64, false, false, false><<<dim3(ND / 128, M / 64, 2), blk, 0, stream>>>(
      aout, Wob, nullptr, nullptr, tmpf, M, ND, ND);
  // 4) h = LN(x + p0 + p1 + bo) -> hf (f32) + hb (bf16)
  add_ln_kernel<true><<<dim3(M), blk, 0, stream>>>(
      tmpf, tmpf + (size_t)M * ND, bo, x, ln1a, ln1b, hf, hb);
  // 5) ffn1 = relu(h @ W1^T + b1) -> bf16
  gemm_bt<128, true, true, true><<<dim3(NDFF / 128, M / 128), blk, 0, stream>>>(
      hb, W1b, b1, ffn1, nullptr, M, NDFF, ND);
  // 6) W2 partials (split-K x2)
  gemm_bt<64, false, false, false><<<dim3(ND / 128, M / 64, 2), blk, 0, stream>>>(
      ffn1, W2b, nullptr, nullptr, tmpf, M, ND, NDFF);
  // 7) out = LN(hf + p0 + p1 + b2) -> f32 d_out
  add_ln_kernel<false><<<dim3(M), blk, 0, stream>>>(
      tmpf, tmpf + (size_t)M * ND, b2, hf, ln2a, ln2b, (float*)d_out, nullptr);
}

// Round 7
// 360.585 us; speedup vs baseline: 1.1756x; 1.0718x over previous
//
#include <hip/hip_runtime.h>
#include <cstdint>
#include <cstddef>

#define NB 2
#define NL 2048
#define ND 1024
#define NH 16
#define NDH 64
#define NDFF 4096

typedef __bf16 bf16_t;
typedef bf16_t bf16x8 __attribute__((ext_vector_type(8)));
typedef float f32x4 __attribute__((ext_vector_type(4)));

__device__ __forceinline__ float bf2f(unsigned short h) {
  union { unsigned u; float f; } c; c.u = ((unsigned)h) << 16; return c.f;
}
__device__ __forceinline__ unsigned short f2bf(float f) {
  union { float f; unsigned u; } c; c.f = f;
  return (unsigned short)((c.u + 0x7fffu + ((c.u >> 16) & 1u)) >> 16);
}

// async global->LDS, 16B per lane; lds base must be wave-uniform.
__device__ __forceinline__ void async_copy16(const void* g, void* l) {
  __builtin_amdgcn_global_load_lds(
      (const __attribute__((address_space(1))) void*)g,
      (__attribute__((address_space(3))) void*)l, 16, 0, 0);
}

// ---------------------------------------------------------------------------
// Fused f32 -> bf16 cast of x + all 4 weight matrices, one launch.
// ---------------------------------------------------------------------------
__global__ __launch_bounds__(256) void cast_all(
    const float* __restrict__ x, const float* __restrict__ wqkv,
    const float* __restrict__ wo, const float* __restrict__ w1,
    const float* __restrict__ w2, unsigned short* __restrict__ xb,
    unsigned short* __restrict__ wqkvb, unsigned short* __restrict__ wob,
    unsigned short* __restrict__ w1b, unsigned short* __restrict__ w2b) {
  const int i = blockIdx.x * 256 + threadIdx.x;
  const float* src;
  unsigned short* dst;
  int off;
  if (i < 1048576) { src = x; dst = xb; off = i; }  // 4M elems (vec4)
  else if (i < 1835008) { src = wqkv; dst = wqkvb; off = i - 1048576; }
  else if (i < 2097152) { src = wo; dst = wob; off = i - 1835008; }
  else if (i < 3145728) { src = w1; dst = w1b; off = i - 2097152; }
  else { src = w2; dst = w2b; off = i - 3145728; }
  const float4 v = ((const float4*)src)[off];
  ushort4 o;
  o.x = f2bf(v.x); o.y = f2bf(v.y); o.z = f2bf(v.z); o.w = f2bf(v.w);
  ((ushort4*)dst)[off] = o;
}

// ---------------------------------------------------------------------------
// GEMM: C[M,N] = A[M,K] @ W[N,K]^T (+ bias[N]) (A,W bf16; C bf16/f32)
// BMx128 tile, BK=32, 4 waves 2x2. Double-buffered LDS, global_load_lds
// width-16, one barrier per K-iter. Split-K via gridDim.z writes f32
// partials at outf + z*M*N; summed downstream in the LN kernel.
// ---------------------------------------------------------------------------
template <int BM, bool RELU, bool OUT_BF16, bool BIAS>
__global__ __launch_bounds__(256, 2) void gemm_bt(
    const unsigned short* __restrict__ A, const unsigned short* __restrict__ W,
    const float* __restrict__ bias, unsigned short* __restrict__ outb,
    float* __restrict__ outf, int M, int N, int K) {
  constexpr int MI = BM / 32;   // mfma m-tiles per wave (4 or 2)
  constexpr int ACP = BM / 64;  // A staging copies (2 or 1)
  const int tid = threadIdx.x;
  const int wave = tid >> 6, lane = tid & 63;
  const int quad = lane >> 4, l16 = lane & 15;
  const int wm = wave & 1, wn = wave >> 1;
  const int m0 = blockIdx.y * BM, n0 = blockIdx.x * 128;
  const int kz = blockIdx.z;
  const int Kh = K / gridDim.z;  // this block's K extent
  const int kof = kz * Kh;       // this block's K start

  __shared__ __align__(16) unsigned short As[2][BM * 32];
  __shared__ __align__(16) unsigned short Bs[2][128 * 32];

  const int r0 = tid >> 2;       // 0..63
  const int kc = (tid & 3) * 8;  // 0,8,16,24
  const unsigned short* Ag[ACP];
#pragma unroll
  for (int i = 0; i < ACP; i++)
    Ag[i] = A + (size_t)(m0 + r0 + 64 * i) * K + kof + kc;
  const unsigned short* Bg[2];
#pragma unroll
  for (int i = 0; i < 2; i++)
    Bg[i] = W + (size_t)(n0 + r0 + 64 * i) * K + kof + kc;

  f32x4 acc[MI][4];
#pragma unroll
  for (int i = 0; i < MI; i++)
#pragma unroll
    for (int j = 0; j < 4; j++) acc[i][j] = (f32x4){0.f, 0.f, 0.f, 0.f};

  auto stage = [&](int koff, int bsel) {
#pragma unroll
    for (int i = 0; i < ACP; i++)
      async_copy16(Ag[i] + koff, &As[bsel][(i * 256 + wave * 64) * 8]);
#pragma unroll
    for (int i = 0; i < 2; i++)
      async_copy16(Bg[i] + koff, &Bs[bsel][(i * 256 + wave * 64) * 8]);
  };

  stage(0, 0);
  int buf = 0;
  for (int k0 = 0; k0 < Kh; k0 += 32) {
    __syncthreads();  // tile k ready in buf; prior reads of buf^1 done
    if (k0 + 32 < Kh) stage(k0 + 32, buf ^ 1);  // overlap with compute
    bf16x8 af[MI], bfr[4];
#pragma unroll
    for (int i = 0; i < MI; i++)
      af[i] =
          *(const bf16x8*)&As[buf][(wm * (MI * 16) + i * 16 + l16) * 32 + quad * 8];
#pragma unroll
    for (int j = 0; j < 4; j++)
      bfr[j] = *(const bf16x8*)&Bs[buf][(wn * 64 + j * 16 + l16) * 32 + quad * 8];
#pragma unroll
    for (int i = 0; i < MI; i++)
#pragma unroll
      for (int j = 0; j < 4; j++)
        acc[i][j] =
            __builtin_amdgcn_mfma_f32_16x16x32_bf16(af[i], bfr[j], acc[i][j], 0, 0, 0);
    buf ^= 1;
  }

  float* outp = outf + (size_t)kz * M * N;  // partial slot (split-K)
#pragma unroll
  for (int j = 0; j < 4; j++) {
    const int col = n0 + wn * 64 + j * 16 + l16;
    const float bj = BIAS ? bias[col] : 0.f;
#pragma unroll
    for (int i = 0; i < MI; i++) {
      const int rowb = m0 + wm * (MI * 16) + i * 16 + quad * 4;
#pragma unroll
      for (int r = 0; r < 4; r++) {
        float v = acc[i][j][r] + bj;
        if (RELU) v = v > 0.f ? v : 0.f;
        const size_t idx = (size_t)(rowb + r) * N + col;
        if (OUT_BF16) outb[idx] = f2bf(v);
        else outp[idx] = v;
      }
    }
  }
}

// ---------------------------------------------------------------------------
// MFMA flash attention, causal. qkv: [B*L][3*ND] bf16, row = [q | k | v].
// 64-row q-tiles: grid (32 bh, 32 tiles) = 1024 blocks (4/CU, 4 waves/SIMD
// for latency hiding). Block = 4 waves; wave w owns 16 q-rows
// (qwb = 64*t + 16*w). K/V chunks of 64. S^T = K·Q^T (per-lane softmax).
// Tile index t permuted so each CU's 4 resident blocks sum to equal work
// and heaviest tiles dispatch first.
// ---------------------------------------------------------------------------
__global__ __launch_bounds__(256, 4) void attn_mfma(
    const unsigned short* __restrict__ qkv, unsigned short* __restrict__ out) {
  const int tid = threadIdx.x;
  const int w = tid >> 6, lane = tid & 63;
  const int quad = lane >> 4, l16 = lane & 15;
  const int bh = blockIdx.x;
  const int b = bh >> 4, h = bh & 15;
  const int y = blockIdx.y;
  // t map: y in [0,8)->31-y, [8,16)->y-8, [16,24)->39-y, [24,32)->y-16.
  // CU sees y-set {y0, y0+8, y0+16, y0+24}: work sums to 62 for all y0.
  const int t = (y < 8) ? (31 - y) : (y < 16) ? (y - 8) : (y < 24) ? (39 - y)
                                                                   : (y - 16);
  const int qwb = t * 64 + w * 16;  // wave's first q row

  __shared__ __align__(16) unsigned short Ks[64 * 72];     // [k][d]
  __shared__ __align__(16) unsigned short Vt[64 * 72];     // [d][k-swizzled]
  __shared__ __align__(16) unsigned short Pw[4][16 * 72];  // per-wave P [q][k]

  // Q B-frags (x0.125 folded, exact): qb[kd], elem j = Q[qwb+l16][kd*32+quad*8+j]
  bf16x8 qb[2];
#pragma unroll
  for (int kd = 0; kd < 2; kd++) {
    const unsigned short* qp =
        qkv + (size_t)(b * NL + qwb + l16) * (3 * ND) + h * NDH + kd * 32 + quad * 8;
    union { uint4 u; unsigned short s[8]; bf16x8 v; } qu;
    qu.u = *(const uint4*)qp;
#pragma unroll
    for (int e = 0; e < 8; e++) qu.s[e] = f2bf(bf2f(qu.s[e]) * 0.125f);
    qb[kd] = qu.v;
  }

  float m_s = -INFINITY, l_s = 0.f;
  f32x4 of_[4];
#pragma unroll
  for (int nd = 0; nd < 4; nd++) of_[nd] = (f32x4){0.f, 0.f, 0.f, 0.f};

  const int nch = t + 1;
  for (int c = 0; c < nch; c++) {
    const int kbase = c * 64;
    __syncthreads();  // prior chunk's Ks/Vt reads complete
    // ---- stage K (row-major) and V (transposed, swizzled k-groups) ----
#pragma unroll
    for (int p = 0; p < 2; p++) {
      const int kk = p * 32 + (tid >> 3);
      const int d0 = (tid & 7) * 8;
      const unsigned short* gk =
          qkv + (size_t)(b * NL + kbase + kk) * (3 * ND) + ND + h * NDH + d0;
      uint4 ku = *(const uint4*)gk;
      uint4 vu = *(const uint4*)(gk + ND);
      *(uint4*)&Ks[kk * 72 + d0] = ku;
      const unsigned short* pv = (const unsigned short*)&vu;
      const int kg = kk >> 3, kr = kk & 7;
#pragma unroll
      for (int e = 0; e < 8; e++) {
        const int d = d0 + e;
        Vt[d * 72 + ((kg ^ (d >> 3)) & 7) * 8 + kr] = pv[e];
      }
    }
    __syncthreads();

    // ---- S^T = K·Q^T: st[kt], row=k(quad*4+reg), col=q(l16) ----
    f32x4 st[4];
#pragma unroll
    for (int kt = 0; kt < 4; kt++) st[kt] = (f32x4){0.f, 0.f, 0.f, 0.f};
#pragma unroll
    for (int kd = 0; kd < 2; kd++)
#pragma unroll
      for (int kt = 0; kt < 4; kt++) {
        const bf16x8 kaf =
            *(const bf16x8*)&Ks[(kt * 16 + l16) * 72 + kd * 32 + quad * 8];
        st[kt] = __builtin_amdgcn_mfma_f32_16x16x32_bf16(kaf, qb[kd], st[kt], 0, 0, 0);
      }

    // ---- causal mask (boundary chunk only: c == t) ----
    if (kbase + 63 > qwb) {
      const int qg_ = qwb + l16;
#pragma unroll
      for (int kt = 0; kt < 4; kt++) {
        const int kg_ = kbase + kt * 16 + quad * 4;
#pragma unroll
        for (int r = 0; r < 4; r++)
          if (kg_ + r > qg_) st[kt][r] = -INFINITY;
      }
    }

    // ---- online softmax (per-lane rows; quad-reduce via shfl_xor) ----
    float mx = -INFINITY;
#pragma unroll
    for (int kt = 0; kt < 4; kt++)
#pragma unroll
      for (int r = 0; r < 4; r++) mx = fmaxf(mx, st[kt][r]);
    mx = fmaxf(mx, __shfl_xor(mx, 16, 64));
    mx = fmaxf(mx, __shfl_xor(mx, 32, 64));
    const float mnew = fmaxf(m_s, mx);
    const float al = __expf(m_s - mnew);  // first chunk: exp(-inf)=0
    m_s = mnew;
    float sum = 0.f;
#pragma unroll
    for (int kt = 0; kt < 4; kt++) {
      ushort4 pk_;
#pragma unroll
      for (int r = 0; r < 4; r++) {
        const float p = __expf(st[kt][r] - mnew);
        sum += p;
        ((unsigned short*)&pk_)[r] = f2bf(p);
      }
      *(ushort4*)&Pw[w][l16 * 72 + kt * 16 + quad * 4] = pk_;
    }
    sum += __shfl_xor(sum, 16, 64);
    sum += __shfl_xor(sum, 32, 64);
    l_s = l_s * al + sum;

    // ---- O rescale by alpha (broadcast to C-layout rows) ----
#pragma unroll
    for (int r = 0; r < 4; r++) {
      const float ar = __shfl(al, quad * 4 + r, 16);
#pragma unroll
      for (int nd = 0; nd < 4; nd++) of_[nd][r] *= ar;
    }

    // ---- O += P·V ----
#pragma unroll
    for (int kk = 0; kk < 2; kk++) {
      const bf16x8 pa = *(const bf16x8*)&Pw[w][l16 * 72 + kk * 32 + quad * 8];
#pragma unroll
      for (int nd = 0; nd < 4; nd++) {
        const int d = nd * 16 + l16;
        const bf16x8 vbf =
            *(const bf16x8*)&Vt[d * 72 + (((kk * 4 + quad) ^ (d >> 3)) & 7) * 8];
        of_[nd] = __builtin_amdgcn_mfma_f32_16x16x32_bf16(pa, vbf, of_[nd], 0, 0, 0);
      }
    }
  }

  // ---- normalize + write O (row q = quad*4+reg, col d = l16) ----
  const float li = 1.f / l_s;
#pragma unroll
  for (int r = 0; r < 4; r++) {
    const float lr = __shfl(li, quad * 4 + r, 16);
    const size_t rowoff = (size_t)(b * NL + qwb + quad * 4 + r) * ND + h * NDH;
#pragma unroll
    for (int nd = 0; nd < 4; nd++)
      out[rowoff + nd * 16 + l16] = f2bf(of_[nd][r] * lr);
  }
}

// ---------------------------------------------------------------------------
// (p0 + p1 + bias + res) -> LayerNorm (ddof=1). All f32; optional bf16 copy.
// ---------------------------------------------------------------------------
__device__ __forceinline__ float block_sum256(float v, float* sbuf) {
#pragma unroll
  for (int off = 32; off > 0; off >>= 1) v += __shfl_down(v, off, 64);
  const int tid = threadIdx.x;
  if ((tid & 63) == 0) sbuf[tid >> 6] = v;
  __syncthreads();
  return sbuf[0] + sbuf[1] + sbuf[2] + sbuf[3];
}

template <bool WRITE_BF16>
__global__ __launch_bounds__(256, 4) void add_ln_kernel(
    const float* __restrict__ p0, const float* __restrict__ p1,
    const float* __restrict__ bias, const float* __restrict__ res,
    const float* __restrict__ gam, const float* __restrict__ bet,
    float* __restrict__ of, unsigned short* __restrict__ ob) {
  const int row = blockIdx.x, tid = threadIdx.x;
  __shared__ float sbuf[4];
  const size_t base = (size_t)row * ND;
  float x[4];
#pragma unroll
  for (int e = 0; e < 4; e++) {
    const int idx = tid + 256 * e;
    x[e] = p0[base + idx] + p1[base + idx] + bias[idx] + res[base + idx];
  }
  float s = x[0] + x[1] + x[2] + x[3];
  s = block_sum256(s, sbuf);
  const float mean = s * (1.f / (float)ND);
  float sq = 0.f;
#pragma unroll
  for (int e = 0; e < 4; e++) {
    const float d = x[e] - mean;
    sq += d * d;
  }
  __syncthreads();
  sq = block_sum256(sq, sbuf);
  const float inv = 1.f / (sqrtf(sq * (1.f / (float)(ND - 1))) + 1e-6f);
#pragma unroll
  for (int e = 0; e < 4; e++) {
    const int idx = tid + 256 * e;
    const float y = (x[e] - mean) * inv * gam[idx] + bet[idx];
    of[base + idx] = y;
    if (WRITE_BF16) ob[base + idx] = f2bf(y);
  }
}

// ---------------------------------------------------------------------------
extern "C" void kernel_launch(void* const* d_in, const int* in_sizes, int n_in,
                              void* d_out, int out_size, void* d_ws, size_t ws_size,
                              hipStream_t stream) {
  const float* x = (const float*)d_in[0];
  // d_in[1] = mask (int32) — exactly causal, handled analytically
  const float* Wqkv = (const float*)d_in[2];
  const float* bqkv = (const float*)d_in[3];
  const float* Wo = (const float*)d_in[4];
  const float* bo = (const float*)d_in[5];
  const float* ln1a = (const float*)d_in[6];
  const float* ln1b = (const float*)d_in[7];
  const float* W1 = (const float*)d_in[8];
  const float* b1 = (const float*)d_in[9];
  const float* W2 = (const float*)d_in[10];
  const float* b2 = (const float*)d_in[11];
  const float* ln2a = (const float*)d_in[12];
  const float* ln2b = (const float*)d_in[13];

  // workspace layout (MiB); peak 112 MiB; every region single-writer-then-
  // reader per step (lifetimes verified in round 6):
  //  [0,24) qkv (1-2) / [0,32) ffn1 (5-6) | [24,32) aout (2-3)
  //  [32,64) tmpf: two contiguous 16-MiB f32 partials (Wo 3-4; W2 6-7)
  //  [64,80) hf (4-7) | [80,88) xb (0-1)
  //  [88,94) Wqkvb (0-1) | [94,96) Wob (0-3) | [88,96) hb (4-5, overlays)
  //  [96,104) W1b (0-5) | [104,112) W2b (0-6)
  char* ws = (char*)d_ws;
  unsigned short* qkv = (unsigned short*)(ws);
  unsigned short* ffn1 = (unsigned short*)(ws);
  unsigned short* aout = (unsigned short*)(ws + 25165824);
  float* tmpf = (float*)(ws + 33554432);
  float* hf = (float*)(ws + 67108864);
  unsigned short* xb = (unsigned short*)(ws + 83886080);
  unsigned short* Wqkvb = (unsigned short*)(ws + 92274688);
  unsigned short* Wob = (unsigned short*)(ws + 98566144);
  unsigned short* hb = (unsigned short*)(ws + 92274688);
  unsigned short* W1b = (unsigned short*)(ws + 100663296);
  unsigned short* W2b = (unsigned short*)(ws + 109051904);

  const int M = NB * NL;  // 4096
  dim3 blk(256);

  // 0) all f32->bf16 casts in one launch
  cast_all<<<dim3(16384), blk, 0, stream>>>(x, Wqkv, Wo, W1, W2, xb, Wqkvb, Wob,
                                            W1b, W2b);
  // 1) qkv = x @ Wqkv^T + bqkv -> bf16
  gemm_bt<128, false, true, true><<<dim3(3 * ND / 128, M / 128), blk, 0, stream>>>(
      xb, Wqkvb, bqkv, qkv, nullptr, M, 3 * ND, ND);
  // 2) attention -> aout bf16 (64-row q-tiles, 1024 blocks)
  attn_mfma<<<dim3(NB * NH, NL / 64), blk, 0, stream>>>(qkv, aout);
  // 3) Wo partials (split-K x2 -> 1024 blocks): tmpf + z*M*N
  gemm_bt<64, false, false, false><<<dim3(ND / 128, M / 64, 2), blk, 0, stream>>>(
      aout, Wob, nullptr, nullptr, tmpf, M, ND, ND);
  // 4) h = LN(x + p0 + p1 + bo) -> hf (f32) + hb (bf16)
  add_ln_kernel<true><<<dim3(M), blk, 0, stream>>>(
      tmpf, tmpf + (size_t)M * ND, bo, x, ln1a, ln1b, hf, hb);
  // 5) ffn1 = relu(h @ W1^T + b1) -> bf16
  gemm_bt<128, true, true, true><<<dim3(NDFF / 128, M / 128), blk, 0, stream>>>(
      hb, W1b, b1, ffn1, nullptr, M, NDFF, ND);
  // 6) W2 partials (split-K x2)
  gemm_bt<64, false, false, false><<<dim3(ND / 128, M / 64, 2), blk, 0, stream>>>(
      ffn1, W2b, nullptr, nullptr, tmpf, M, ND, NDFF);
  // 7) out = LN(hf + p0 + p1 + b2) -> f32 d_out
  add_ln_kernel<false><<<dim3(M), blk, 0, stream>>>(
      tmpf, tmpf + (size_t)M * ND, b2, hf, ln2a, ln2b, (float*)d_out, nullptr);
}